// Round 12
// baseline (202.937 us; speedup 1.0000x reference)
//
#include <hip/hip_runtime.h>
#include <hip/hip_fp16.h>

// ---------------- types ----------------
typedef _Float16 half8_t __attribute__((ext_vector_type(8)));
typedef _Float16 half4_t __attribute__((ext_vector_type(4)));
typedef _Float16 h2      __attribute__((ext_vector_type(2)));
typedef float    f32x4   __attribute__((ext_vector_type(4)));

#define LOG2E 1.4426950408889634f
// SCALE = 1/sqrt(32); fold log2(e) so we can use exp2
#define KSCALE (0.17677669529663687f * LOG2E)

#if __has_builtin(__builtin_amdgcn_exp2f)
#define EXP2F(x) __builtin_amdgcn_exp2f(x)
#else
#define EXP2F(x) exp2f(x)
#endif

// DPP row_ror:N (rotate within 16-lane row) — VALU cross-lane, no LDS pipe.
template <int N>
__device__ __forceinline__ int dpp_ror(int v) {
  return __builtin_amdgcn_update_dpp(0, v, 0x120 + N, 0xf, 0xf, true);
}
// 16-lane max-reduce of two independent f16 values packed in h2.
__device__ __forceinline__ h2 rowmax16_h2(h2 v) {
  int t;
  t = dpp_ror<1>(__builtin_bit_cast(int, v));
  v = __builtin_elementwise_max(v, __builtin_bit_cast(h2, t));
  t = dpp_ror<2>(__builtin_bit_cast(int, v));
  v = __builtin_elementwise_max(v, __builtin_bit_cast(h2, t));
  t = dpp_ror<4>(__builtin_bit_cast(int, v));
  v = __builtin_elementwise_max(v, __builtin_bit_cast(h2, t));
  t = dpp_ror<8>(__builtin_bit_cast(int, v));
  v = __builtin_elementwise_max(v, __builtin_bit_cast(h2, t));
  return v;
}

// ---------------------------------------------------------------------------
// prep: [0,48)  Wqkv^T via LDS 64x64 tile transpose; [48,64) Wout^T;
//       [64,80) coords layer-1 precompute
// ---------------------------------------------------------------------------
__global__ __launch_bounds__(256) void prep_misc(
    const float* __restrict__ Wqkv, const float* __restrict__ Wout,
    const float* __restrict__ coords,
    const float* __restrict__ pw1, const float* __restrict__ pb1,
    const float* __restrict__ sw1, const float* __restrict__ sb1,
    _Float16* __restrict__ WqkvT, _Float16* __restrict__ WoutT,
    _Float16* __restrict__ APre, _Float16* __restrict__ BPre)
{
  __shared__ float tile[64][65];
  const int bi = blockIdx.x, tid = threadIdx.x;
  if (bi < 64) {                         // W transposes, 64x64 tiles
    const float* src; _Float16* dst; int t, W;  // W = src row width
    if (bi < 48) { t = bi;      src = Wqkv; dst = WqkvT; W = 768; }
    else         { t = bi - 48; src = Wout; dst = WoutT; W = 256; }
    const int nOT = W >> 6;              // o-tiles per k-row
    const int tk = t / nOT, to = t % nOT;
    const int cx = tid & 63, ry = tid >> 6;
#pragma unroll
    for (int rr = 0; rr < 16; ++rr) {
      const int kl = rr * 4 + ry;
      tile[kl][cx] = src[(tk * 64 + kl) * W + to * 64 + cx];
    }
    __syncthreads();
#pragma unroll
    for (int rr = 0; rr < 16; ++rr) {
      const int ol = rr * 4 + ry;
      dst[(to * 64 + ol) * 256 + tk * 64 + cx] = (_Float16)tile[cx][ol];
    }
  } else {                               // coords precompute: 4096 rows
    const int row = (bi - 64) * 256 + tid;
    const float c0 = coords[row * 3 + 0];
    const float c1 = coords[row * 3 + 1];
    const float c2 = coords[row * 3 + 2];
#pragma unroll
    for (int k = 0; k < 16; ++k) {
      float a = c0 * pw1[k] + c1 * pw1[16 + k] + c2 * pw1[32 + k];
      APre[row * 32 + k] = (_Float16)(a + pb1[k]);
      BPre[row * 32 + k] = (_Float16)a;
      float s  =  c0 * sw1[k] + c1 * sw1[16 + k] + c2 * sw1[32 + k];
      float sb = -c0 * sw1[k] + c1 * sw1[16 + k] + c2 * sw1[32 + k];
      APre[row * 32 + 16 + k] = (_Float16)(s + sb1[k]);
      BPre[row * 32 + 16 + k] = (_Float16)sb;
    }
  }
}

// ---------------------------------------------------------------------------
// qkv_gemm: x f32 read directly (cast in-flight); epilogues via per-wave LDS
// transpose -> coalesced 16B stores (round 8/9 version, kept).
// ---------------------------------------------------------------------------
__global__ __launch_bounds__(256) void qkv_gemm(
    const float* __restrict__ x, const _Float16* __restrict__ WqkvT,
    _Float16* __restrict__ Qh, _Float16* __restrict__ Kh,
    _Float16* __restrict__ Vt)
{
  __shared__ __align__(16) _Float16 tbuf[4][1536];
  const int wv = threadIdx.x >> 6;
  const int wg = blockIdx.x * 4 + wv;
  const int ti = wg / 12, og = wg % 12;
  const int i0 = ti * 16, o0 = og * 64;
  const int lane = threadIdx.x & 63, q = lane >> 4, c = lane & 15;
  f32x4 acc[4] = {{0,0,0,0},{0,0,0,0},{0,0,0,0},{0,0,0,0}};
  const float*    arow = x + (i0 + c) * 256;
  const _Float16* brow = WqkvT + (o0 + c) * 256;
#pragma unroll
  for (int k0 = 0; k0 < 256; k0 += 32) {
    f32x4 a0 = *reinterpret_cast<const f32x4*>(arow + k0 + q * 8);
    f32x4 a1 = *reinterpret_cast<const f32x4*>(arow + k0 + q * 8 + 4);
    half8_t af;
    af[0] = (_Float16)a0[0]; af[1] = (_Float16)a0[1];
    af[2] = (_Float16)a0[2]; af[3] = (_Float16)a0[3];
    af[4] = (_Float16)a1[0]; af[5] = (_Float16)a1[1];
    af[6] = (_Float16)a1[2]; af[7] = (_Float16)a1[3];
#pragma unroll
    for (int t = 0; t < 4; ++t) {
      half8_t bf = *reinterpret_cast<const half8_t*>(brow + t * 16 * 256 + k0 + q * 8);
      acc[t] = __builtin_amdgcn_mfma_f32_16x16x32_f16(af, bf, acc[t], 0, 0, 0);
    }
  }
  const int b = i0 >> 11, n0 = i0 & 2047;
  _Float16* vt = tbuf[wv];
  if (og < 8) {                          // Q / K epilogue via LDS transpose
#pragma unroll
    for (int t = 0; t < 4; ++t)
#pragma unroll
      for (int r = 0; r < 4; ++r)
        vt[(q * 4 + r) * 72 + t * 16 + c] = (_Float16)acc[t][r];
    asm volatile("s_waitcnt lgkmcnt(0)" ::: "memory");   // wave-private tile
    __builtin_amdgcn_sched_barrier(0);
    const int nl = lane & 15, seg = lane >> 4;
    const int o_g = o0 + seg * 16;                 // wave-uniform Q-vs-K split
    const int h = (o_g >> 5) & 7, dbase = o_g & 31;
    _Float16* dst = ((o_g >> 8) == 0 ? Qh : Kh) +
                    ((b * 8 + h) * 2048 + n0 + nl) * 32 + dbase;
    half8_t r0 = *reinterpret_cast<const half8_t*>(vt + nl * 72 + seg * 16);
    half8_t r1 = *reinterpret_cast<const half8_t*>(vt + nl * 72 + seg * 16 + 8);
    *reinterpret_cast<half8_t*>(dst)     = r0;
    *reinterpret_cast<half8_t*>(dst + 8) = r1;
  } else {                               // V epilogue via LDS transpose
#pragma unroll
    for (int t = 0; t < 4; ++t)
#pragma unroll
      for (int r = 0; r < 4; ++r)
        vt[(t * 16 + c) * 24 + q * 4 + r] = (_Float16)acc[t][r];
    asm volatile("s_waitcnt lgkmcnt(0)" ::: "memory");
    __builtin_amdgcn_sched_barrier(0);
    const long row = (long)(b * 256 + (o0 - 512) + lane);
    half8_t r0 = *reinterpret_cast<const half8_t*>(vt + lane * 24);
    half8_t r1 = *reinterpret_cast<const half8_t*>(vt + lane * 24 + 8);
    *reinterpret_cast<half8_t*>(Vt + row * 2048 + n0)     = r0;
    *reinterpret_cast<half8_t*>(Vt + row * 2048 + n0 + 8) = r1;
  }
}

// ---------------------------------------------------------------------------
// flash: THIS ROUND (r11 decoupling was null — 60.2->60.8):
//   * K/V REGISTER PREFETCH one tile ahead — scores consume regs loaded a
//     full iteration earlier (same mechanism as r10's bpf win; compiler
//     cannot hoist global loads across __syncthreads itself).
//   * bias_prod moved AFTER PV: the pbuf lgkmcnt(0) fence now drains only
//     the 8 pbuf writes; bias MFMA/VALU overlaps PV latency + wave skew.
//   * merged A/B rescale trigger (one __any/branch per tile; exact).
// NOTE: (512,4) mandatory — (512,6) spilled (r4); KVBLK=64 2-stream spilled
// (r6). Occupancy is NOT the lever (r5 nck=8 null).
// ---------------------------------------------------------------------------
__global__ __launch_bounds__(512, 4) void flash(
    const _Float16* __restrict__ Qh, const _Float16* __restrict__ Kh,
    const _Float16* __restrict__ Vt, const _Float16* __restrict__ APre,
    const _Float16* __restrict__ BPre, const float* __restrict__ pw2,
    const float* __restrict__ sw2, _Float16* __restrict__ Opart,
    float* __restrict__ Mpart)
{
  __shared__ __align__(16) unsigned char smem[53504];
  _Float16* biasH = reinterpret_cast<_Float16*>(smem);          // [2][8h*1160] f16
  _Float16* pbuf  = reinterpret_cast<_Float16*>(smem + 37120);  // [8w][2][16 x 32] f16

  const int blk = blockIdx.x;
  const int b     = blk >> 8;
  const int chunk = (blk >> 6) & 3;
  const int i0    = (blk & 63) << 5;
  const int tid = threadIdx.x;
  const int w = tid >> 6, lane = tid & 63;
  const int q = lane >> 4, c = lane & 15;

  // Q fragments (A-operand): stream A rows i0+c, stream B rows i0+16+c
  const _Float16* qbase = Qh + ((b * 8 + w) * 2048 + i0) * 32;
  half8_t qfA = *reinterpret_cast<const half8_t*>(qbase + c * 32 + q * 8);
  half8_t qfB = *reinterpret_cast<const half8_t*>(qbase + (16 + c) * 32 + q * 8);
  // APre fragments for bias-MFMA A side, j-invariant
  const _Float16* abase = APre + (b * 2048 + i0) * 32;
  half8_t apfA = *reinterpret_cast<const half8_t*>(abase + c * 32 + q * 8);
  half8_t apfB = *reinterpret_cast<const half8_t*>(abase + (16 + c) * 32 + q * 8);

  // stacked W2 B-fragment: B[k][n], k<16 -> pos_w2, k>=16 -> sym_w2; *LOG2E
  half8_t w2f;
#pragma unroll
  for (int jj = 0; jj < 8; ++jj) {
    const int k = q * 8 + jj;
    float val = 0.f;
    if (c < 8) val = (k < 16 ? pw2[k * 8 + c] : sw2[(k - 16) * 8 + c]) * LOG2E;
    w2f[jj] = (_Float16)val;
  }
  half8_t ones8;
#pragma unroll
  for (int jj = 0; jj < 8; ++jj) ones8[jj] = (_Float16)1.0f;

  float mA[4], mB[4];
  f32x4 O0A = {0,0,0,0}, O1A = {0,0,0,0}, O0B = {0,0,0,0}, O1B = {0,0,0,0};
  f32x4 lpA = {0,0,0,0}, lpB = {0,0,0,0};
#pragma unroll
  for (int r = 0; r < 4; ++r) { mA[r] = 0.f; mB[r] = 0.f; }  // m init 0 (exact)

  const f32x4 z4 = {0.f, 0.f, 0.f, 0.f};
  half8_t hzero8 = {};

  const int jbase = chunk * 512;
  const _Float16* BPre_b = BPre + (long)b * 2048 * 32;

  // ---- hoisted per-lane bases/offsets ----
  const int bwoff = c * 1160 + w * 144 + q * 4;   // bias write: + mt*36 (+16 B-half)
  const int broff = w * 1160 + c * 72 + q * 4;    // bias read: +0,+36,+16,+52
  _Float16* pbA = pbuf + w * 1024;
  _Float16* pbB = pbA + 512;
  const int pwo = q * 128 + 2 * c;                // pbuf write: + r*32
  const int pro = c * 32 + q * 8;                 // pbuf read
  const _Float16* kb0 = Kh + ((b * 8 + w) * 2048 + jbase) * 32;
  const _Float16* vb0 = Vt + (b * 8 + w) * 65536 + jbase;
  const int ko0 = (2 * c) * 32 + q * 8, ko1 = ko0 + 32;
  const int vo0 = c * 2048 + q * 8,     vo1 = vo0 + 16 * 2048;
  const _Float16* bpb = BPre_b + (jbase + w * 4) * 32 + q * 8;

  // bias production: writes 4 j-cols x 2 i-halves into bW-base for head c
  auto bias_prod = [&](_Float16* bH, half8_t f0, half8_t f1, half8_t f2,
                       half8_t f3) {
    _Float16* bW = bH + bwoff;
#pragma unroll
    for (int mt = 0; mt < 4; ++mt) {
      half8_t bpf = (mt == 0) ? f0 : (mt == 1) ? f1 : (mt == 2) ? f2 : f3;
      half8_t hvA = __builtin_elementwise_max(apfA - bpf, hzero8);
      f32x4 bcA = __builtin_amdgcn_mfma_f32_16x16x32_f16(hvA, w2f, z4, 0, 0, 0);
      half8_t hvB = __builtin_elementwise_max(apfB - bpf, hzero8);
      f32x4 bcB = __builtin_amdgcn_mfma_f32_16x16x32_f16(hvB, w2f, z4, 0, 0, 0);
      if (c < 8) {   // [h=c][j=w*4+mt][i], j-stride 36, h-stride 1160
        half4_t b4;
        b4[0] = (_Float16)bcA[0]; b4[1] = (_Float16)bcA[1];
        b4[2] = (_Float16)bcA[2]; b4[3] = (_Float16)bcA[3];
        *reinterpret_cast<half4_t*>(bW + mt * 36) = b4;
        half4_t b5;
        b5[0] = (_Float16)bcB[0]; b5[1] = (_Float16)bcB[1];
        b5[2] = (_Float16)bcB[2]; b5[3] = (_Float16)bcB[3];
        *reinterpret_cast<half4_t*>(bW + mt * 36 + 16) = b5;
      }
    }
  };

  // ---- persistent prefetch registers (loaded one tile ahead) ----
  half8_t kfP0, kfP1, vfP0, vfP1;        // K/V for the NEXT tile to compute
  half8_t pf0, pf1, pf2, pf3;            // BPre for the NEXT tile to produce

  // ---- prologue: K/V tile 0; bias tile 0 -> buf0; BPre tile 1 ----
  kfP0 = *reinterpret_cast<const half8_t*>(kb0 + ko0);
  kfP1 = *reinterpret_cast<const half8_t*>(kb0 + ko1);
  vfP0 = *reinterpret_cast<const half8_t*>(vb0 + vo0);
  vfP1 = *reinterpret_cast<const half8_t*>(vb0 + vo1);
  {
    half8_t t0 = *reinterpret_cast<const half8_t*>(bpb);
    half8_t t1 = *reinterpret_cast<const half8_t*>(bpb + 32);
    half8_t t2 = *reinterpret_cast<const half8_t*>(bpb + 64);
    half8_t t3 = *reinterpret_cast<const half8_t*>(bpb + 96);
    bias_prod(biasH, t0, t1, t2, t3);
  }
  pf0 = *reinterpret_cast<const half8_t*>(bpb + 1024);
  pf1 = *reinterpret_cast<const half8_t*>(bpb + 1024 + 32);
  pf2 = *reinterpret_cast<const half8_t*>(bpb + 1024 + 64);
  pf3 = *reinterpret_cast<const half8_t*>(bpb + 1024 + 96);
  __syncthreads();   // bias tile 0 visible

  auto tile = [&](const int jt, _Float16* bufR, _Float16* bufW,
                  const bool last) {
    // ---- 1. bias-read jt (written before the last barrier) ----
    const _Float16* bR = bufR + broff;
    half4_t bbA0 = *reinterpret_cast<const half4_t*>(bR);
    half4_t bbA1 = *reinterpret_cast<const half4_t*>(bR + 36);
    half4_t bbB0 = *reinterpret_cast<const half4_t*>(bR + 16);
    half4_t bbB1 = *reinterpret_cast<const half4_t*>(bR + 52);

    // ---- 2. scores from PREFETCHED K/V regs; keep V for PV ----
    half8_t kf0 = kfP0, kf1 = kfP1, vf0 = vfP0, vf1 = vfP1;
    f32x4 sA0 = __builtin_amdgcn_mfma_f32_16x16x32_f16(qfA, kf0, z4, 0, 0, 0);
    f32x4 sA1 = __builtin_amdgcn_mfma_f32_16x16x32_f16(qfA, kf1, z4, 0, 0, 0);
    f32x4 sB0 = __builtin_amdgcn_mfma_f32_16x16x32_f16(qfB, kf0, z4, 0, 0, 0);
    f32x4 sB1 = __builtin_amdgcn_mfma_f32_16x16x32_f16(qfB, kf1, z4, 0, 0, 0);

    // ---- 3. reload K/V prefetch for jt+1 ----
    {
      const int jn = last ? jt : jt + 1;
      const _Float16* kbase = kb0 + jn * 1024;
      const _Float16* vbase = vb0 + jn * 32;
      kfP0 = *reinterpret_cast<const half8_t*>(kbase + ko0);
      kfP1 = *reinterpret_cast<const half8_t*>(kbase + ko1);
      vfP0 = *reinterpret_cast<const half8_t*>(vbase + vo0);
      vfP1 = *reinterpret_cast<const half8_t*>(vbase + vo1);
    }

    // ---- 4. softmax both streams (bbm fold); merged rescale trigger ----
    float pA0[4], pA1[4], pB0[4], pB1[4];
    float svA0[4], svA1[4], svB0[4], svB1[4];
#pragma unroll
    for (int r = 0; r < 4; ++r) {
      svA0[r] = fmaf(sA0[r], KSCALE, (float)bbA0[r] - mA[r]);
      svA1[r] = fmaf(sA1[r], KSCALE, (float)bbA1[r] - mA[r]);
      svB0[r] = fmaf(sB0[r], KSCALE, (float)bbB0[r] - mB[r]);
      svB1[r] = fmaf(sB1[r], KSCALE, (float)bbB1[r] - mB[r]);
      pA0[r] = EXP2F(svA0[r]);
      pA1[r] = EXP2F(svA1[r]);
      pB0[r] = EXP2F(svB0[r]);
      pB1[r] = EXP2F(svB1[r]);
    }
    {
      float needA = fmaxf(fmaxf(fmaxf(svA0[0], svA1[0]), fmaxf(svA0[1], svA1[1])),
                          fmaxf(fmaxf(svA0[2], svA1[2]), fmaxf(svA0[3], svA1[3])));
      float needB = fmaxf(fmaxf(fmaxf(svB0[0], svB1[0]), fmaxf(svB0[1], svB1[1])),
                          fmaxf(fmaxf(svB0[2], svB1[2]), fmaxf(svB0[3], svB1[3])));
      if (__any(fmaxf(needA, needB) > 4.0f)) {   // rare: reduce+rescale BOTH
        float mrA[4], mrB[4];
#pragma unroll
        for (int r = 0; r < 4; ++r) {
          mrA[r] = fmaxf(svA0[r], svA1[r]) + mA[r];
          mrB[r] = fmaxf(svB0[r], svB1[r]) + mB[r];
        }
        h2 a01, a23, b01, b23;
        a01[0] = (_Float16)mrA[0]; a01[1] = (_Float16)mrA[1];
        a23[0] = (_Float16)mrA[2]; a23[1] = (_Float16)mrA[3];
        b01[0] = (_Float16)mrB[0]; b01[1] = (_Float16)mrB[1];
        b23[0] = (_Float16)mrB[2]; b23[1] = (_Float16)mrB[3];
        a01 = rowmax16_h2(a01); a23 = rowmax16_h2(a23);
        b01 = rowmax16_h2(b01); b23 = rowmax16_h2(b23);
        float mredA[4] = {(float)a01[0], (float)a01[1], (float)a23[0], (float)a23[1]};
        float mredB[4] = {(float)b01[0], (float)b01[1], (float)b23[0], (float)b23[1]};
#pragma unroll
        for (int r = 0; r < 4; ++r) {
          const float mnA = fmaxf(mA[r], mredA[r]);
          const float aA = EXP2F(mA[r] - mnA);
          pA0[r] *= aA; pA1[r] *= aA;
          lpA[r] *= aA; O0A[r] *= aA; O1A[r] *= aA;
          mA[r] = mnA;
          const float mnB = fmaxf(mB[r], mredB[r]);
          const float aB = EXP2F(mB[r] - mnB);
          pB0[r] *= aB; pB1[r] *= aB;
          lpB[r] *= aB; O0B[r] *= aB; O1B[r] *= aB;
          mB[r] = mnB;
        }
      }
    }
#pragma unroll
    for (int r = 0; r < 4; ++r) {
      h2 ppA; ppA[0] = (_Float16)pA0[r]; ppA[1] = (_Float16)pA1[r];
      *reinterpret_cast<h2*>(pbA + pwo + r * 32) = ppA;
      h2 ppB; ppB[0] = (_Float16)pB0[r]; ppB[1] = (_Float16)pB1[r];
      *reinterpret_cast<h2*>(pbB + pwo + r * 32) = ppB;
    }

    // ---- 5. fence: only the 8 pbuf writes are outstanding (bias_prod not
    //         yet issued this tile; bias reads consumed by softmax) ----
    asm volatile("s_waitcnt lgkmcnt(0)" ::: "memory");
    __builtin_amdgcn_sched_barrier(0);

    // ---- 6. PV + lp ----
    half8_t pfAx = *reinterpret_cast<const half8_t*>(pbA + pro);
    half8_t pfBx = *reinterpret_cast<const half8_t*>(pbB + pro);
    O0A = __builtin_amdgcn_mfma_f32_16x16x32_f16(pfAx, vf0, O0A, 0, 0, 0);
    O1A = __builtin_amdgcn_mfma_f32_16x16x32_f16(pfAx, vf1, O1A, 0, 0, 0);
    O0B = __builtin_amdgcn_mfma_f32_16x16x32_f16(pfBx, vf0, O0B, 0, 0, 0);
    O1B = __builtin_amdgcn_mfma_f32_16x16x32_f16(pfBx, vf1, O1B, 0, 0, 0);
    lpA = __builtin_amdgcn_mfma_f32_16x16x32_f16(pfAx, ones8, lpA, 0, 0, 0);
    lpB = __builtin_amdgcn_mfma_f32_16x16x32_f16(pfBx, ones8, lpB, 0, 0, 0);

    // ---- 7. bias_prod jt+1 (overlaps PV tails / wave skew); 8. refill pf ----
    if (!last) {
      bias_prod(bufW, pf0, pf1, pf2, pf3);
      const int jn = (jt + 2 < 16) ? (jt + 2) : 15;
      const _Float16* bp = bpb + jn * 1024;
      pf0 = *reinterpret_cast<const half8_t*>(bp);
      pf1 = *reinterpret_cast<const half8_t*>(bp + 32);
      pf2 = *reinterpret_cast<const half8_t*>(bp + 64);
      pf3 = *reinterpret_cast<const half8_t*>(bp + 96);
      __syncthreads();   // prod jt+1 visible for read at jt+1
    }
  };

  // unroll-by-2: dbuf halves are compile-time per call site
  for (int pt = 0; pt < 8; ++pt) {
    tile(2 * pt,     biasH,        biasH + 9280, false);
    tile(2 * pt + 1, biasH + 9280, biasH,        pt == 7);
  }

  // ---- finalize: lp already full row sums (ones-MFMA); no lane reduce ----
#pragma unroll
  for (int r = 0; r < 4; ++r) {
    const float s = lpA[r];
    const float inv = 1.f / s;
    const int n = i0 + q * 4 + r;
    const long base = (long)(((chunk * 2 + b) * 8 + w) * 2048 + n);
    Opart[base * 32 + c]      = (_Float16)(O0A[r] * inv);
    Opart[base * 32 + 16 + c] = (_Float16)(O1A[r] * inv);
    if (c == 0) Mpart[base] = mA[r] + __log2f(s);
  }
#pragma unroll
  for (int r = 0; r < 4; ++r) {
    const float s = lpB[r];
    const float inv = 1.f / s;
    const int n = i0 + 16 + q * 4 + r;
    const long base = (long)(((chunk * 2 + b) * 8 + w) * 2048 + n);
    Opart[base * 32 + c]      = (_Float16)(O0B[r] * inv);
    Opart[base * 32 + 16 + c] = (_Float16)(O1B[r] * inv);
    if (c == 0) Mpart[base] = mB[r] + __log2f(s);
  }
}

// ---------------------------------------------------------------------------
// combine_proj: fused merge of 4 j-chunk partials -> LDS -> proj GEMM.
// ---------------------------------------------------------------------------
__global__ __launch_bounds__(256) void combine_proj(
    const _Float16* __restrict__ Opart, const float* __restrict__ Mpart,
    const _Float16* __restrict__ WoutT, const float* __restrict__ bout,
    float* __restrict__ out)
{
  __shared__ _Float16 aT[16][264];   // 16 rows x 256 cols, +8 pad
  const int i0 = blockIdx.x * 16;    // global row in [0,4096)
  const int b = i0 >> 11;
  const int n0 = i0 & 2047;
  const int tid = threadIdx.x;
  {
    const int row = tid >> 4, cg = tid & 15;   // col group: cols cg*16..+15
    const int n = n0 + row;
    const int h = cg >> 1;
    const int d0 = (cg & 1) * 16;
    float mv[4], M = -INFINITY;
#pragma unroll
    for (int ck = 0; ck < 4; ++ck) {
      mv[ck] = Mpart[((ck * 2 + b) * 8 + h) * 2048 + n];
      M = fmaxf(M, mv[ck]);
    }
    float num[16];
#pragma unroll
    for (int e = 0; e < 16; ++e) num[e] = 0.f;
    float den = 0.f;
#pragma unroll
    for (int ck = 0; ck < 4; ++ck) {
      const float wgt = EXP2F(mv[ck] - M);
      const _Float16* op = Opart +
          (long)(((ck * 2 + b) * 8 + h) * 2048 + n) * 32 + d0;
      half8_t o0v = *reinterpret_cast<const half8_t*>(op);
      half8_t o1v = *reinterpret_cast<const half8_t*>(op + 8);
#pragma unroll
      for (int e = 0; e < 8; ++e) {
        num[e]     += wgt * (float)o0v[e];
        num[8 + e] += wgt * (float)o1v[e];
      }
      den += wgt;
    }
    const float inv = 1.f / den;
    half8_t h0, h1;
#pragma unroll
    for (int e = 0; e < 8; ++e) {
      h0[e] = (_Float16)(num[e] * inv);
      h1[e] = (_Float16)(num[8 + e] * inv);
    }
    *reinterpret_cast<half8_t*>(&aT[row][cg * 16])     = h0;
    *reinterpret_cast<half8_t*>(&aT[row][cg * 16 + 8]) = h1;
  }
  __syncthreads();

  // ---- proj GEMM: wave does 16i x 64o (4 tiles), A from LDS ----
  const int o0 = (tid >> 6) * 64;
  const int lane = tid & 63, q = lane >> 4, c = lane & 15;
  f32x4 acc[4] = {{0,0,0,0},{0,0,0,0},{0,0,0,0},{0,0,0,0}};
  const _Float16* brow = WoutT + (o0 + c) * 256;
#pragma unroll
  for (int k0 = 0; k0 < 256; k0 += 32) {
    half8_t af = *reinterpret_cast<const half8_t*>(&aT[c][k0 + q * 8]);
#pragma unroll
    for (int t = 0; t < 4; ++t) {
      half8_t bf = *reinterpret_cast<const half8_t*>(brow + t * 16 * 256 + k0 + q * 8);
      acc[t] = __builtin_amdgcn_mfma_f32_16x16x32_f16(af, bf, acc[t], 0, 0, 0);
    }
  }
#pragma unroll
  for (int t = 0; t < 4; ++t) {
    const float bo = bout[o0 + t * 16 + c];
#pragma unroll
    for (int r = 0; r < 4; ++r)
      out[(i0 + q * 4 + r) * 256 + o0 + t * 16 + c] = acc[t][r] + bo;
  }
}

// ---------------------------------------------------------------------------
extern "C" void kernel_launch(void* const* d_in, const int* in_sizes, int n_in,
                              void* d_out, int out_size, void* d_ws, size_t ws_size,
                              hipStream_t stream)
{
  const float* x      = (const float*)d_in[0];
  const float* coords = (const float*)d_in[1];
  const float* Wqkv   = (const float*)d_in[2];
  const float* Wout   = (const float*)d_in[3];
  const float* bout   = (const float*)d_in[4];
  const float* pw1    = (const float*)d_in[5];
  const float* pb1    = (const float*)d_in[6];
  const float* pw2    = (const float*)d_in[7];
  const float* sw1    = (const float*)d_in[9];
  const float* sb1    = (const float*)d_in[10];
  const float* sw2    = (const float*)d_in[11];
  float* out = (float*)d_out;

  char* ws = (char*)d_ws;
  _Float16* Qh      = (_Float16*)(ws + 0);         // 2 MB
  _Float16* Kh      = (_Float16*)(ws + 2097152);   // 2 MB
  _Float16* Vt      = (_Float16*)(ws + 4194304);   // 2 MB
  _Float16* WqkvT   = (_Float16*)(ws + 8388608);   // 384 KB
  _Float16* WoutT   = (_Float16*)(ws + 8781824);   // 128 KB
  _Float16* APre    = (_Float16*)(ws + 8912896);   // 256 KB
  _Float16* BPre    = (_Float16*)(ws + 9175040);   // 256 KB
  _Float16* Opart   = (_Float16*)(ws + 9437184);   // 8 MB  [4][2][8][2048][32]
  float*    Mpart   = (float*)   (ws + 17825792);  // 512 KB [4][2][8][2048]

  prep_misc<<<80, 256, 0, stream>>>(Wqkv, Wout, coords, pw1, pb1, sw1, sb1,
                                    WqkvT, WoutT, APre, BPre);
  qkv_gemm<<<768, 256, 0, stream>>>(x, WqkvT, Qh, Kh, Vt);
  flash<<<512, 512, 0, stream>>>(Qh, Kh, Vt, APre, BPre, pw2, sw2, Opart, Mpart);
  combine_proj<<<256, 256, 0, stream>>>(Opart, Mpart, WoutT, bout, out);
}

// Round 13
// 156.900 us; speedup vs baseline: 1.2934x; 1.2934x over previous
//
#include <hip/hip_runtime.h>
#include <hip/hip_fp16.h>

// ---------------- types ----------------
typedef _Float16 half8_t __attribute__((ext_vector_type(8)));
typedef _Float16 half4_t __attribute__((ext_vector_type(4)));
typedef _Float16 h2      __attribute__((ext_vector_type(2)));
typedef float    f32x4   __attribute__((ext_vector_type(4)));

#define LOG2E 1.4426950408889634f
// SCALE = 1/sqrt(32); fold log2(e) so we can use exp2
#define KSCALE (0.17677669529663687f * LOG2E)

#if __has_builtin(__builtin_amdgcn_exp2f)
#define EXP2F(x) __builtin_amdgcn_exp2f(x)
#else
#define EXP2F(x) exp2f(x)
#endif

// DPP row_ror:N (rotate within 16-lane row) — VALU cross-lane, no LDS pipe.
template <int N>
__device__ __forceinline__ int dpp_ror(int v) {
  return __builtin_amdgcn_update_dpp(0, v, 0x120 + N, 0xf, 0xf, true);
}
// 16-lane max-reduce of two independent f16 values packed in h2.
__device__ __forceinline__ h2 rowmax16_h2(h2 v) {
  int t;
  t = dpp_ror<1>(__builtin_bit_cast(int, v));
  v = __builtin_elementwise_max(v, __builtin_bit_cast(h2, t));
  t = dpp_ror<2>(__builtin_bit_cast(int, v));
  v = __builtin_elementwise_max(v, __builtin_bit_cast(h2, t));
  t = dpp_ror<4>(__builtin_bit_cast(int, v));
  v = __builtin_elementwise_max(v, __builtin_bit_cast(h2, t));
  t = dpp_ror<8>(__builtin_bit_cast(int, v));
  v = __builtin_elementwise_max(v, __builtin_bit_cast(h2, t));
  return v;
}

// ---------------------------------------------------------------------------
// prep: [0,48)  Wqkv^T via LDS 64x64 tile transpose; [48,64) Wout^T;
//       [64,80) coords layer-1 precompute
// ---------------------------------------------------------------------------
__global__ __launch_bounds__(256) void prep_misc(
    const float* __restrict__ Wqkv, const float* __restrict__ Wout,
    const float* __restrict__ coords,
    const float* __restrict__ pw1, const float* __restrict__ pb1,
    const float* __restrict__ sw1, const float* __restrict__ sb1,
    _Float16* __restrict__ WqkvT, _Float16* __restrict__ WoutT,
    _Float16* __restrict__ APre, _Float16* __restrict__ BPre)
{
  __shared__ float tile[64][65];
  const int bi = blockIdx.x, tid = threadIdx.x;
  if (bi < 64) {                         // W transposes, 64x64 tiles
    const float* src; _Float16* dst; int t, W;  // W = src row width
    if (bi < 48) { t = bi;      src = Wqkv; dst = WqkvT; W = 768; }
    else         { t = bi - 48; src = Wout; dst = WoutT; W = 256; }
    const int nOT = W >> 6;              // o-tiles per k-row
    const int tk = t / nOT, to = t % nOT;
    const int cx = tid & 63, ry = tid >> 6;
#pragma unroll
    for (int rr = 0; rr < 16; ++rr) {
      const int kl = rr * 4 + ry;
      tile[kl][cx] = src[(tk * 64 + kl) * W + to * 64 + cx];
    }
    __syncthreads();
#pragma unroll
    for (int rr = 0; rr < 16; ++rr) {
      const int ol = rr * 4 + ry;
      dst[(to * 64 + ol) * 256 + tk * 64 + cx] = (_Float16)tile[cx][ol];
    }
  } else {                               // coords precompute: 4096 rows
    const int row = (bi - 64) * 256 + tid;
    const float c0 = coords[row * 3 + 0];
    const float c1 = coords[row * 3 + 1];
    const float c2 = coords[row * 3 + 2];
#pragma unroll
    for (int k = 0; k < 16; ++k) {
      float a = c0 * pw1[k] + c1 * pw1[16 + k] + c2 * pw1[32 + k];
      APre[row * 32 + k] = (_Float16)(a + pb1[k]);
      BPre[row * 32 + k] = (_Float16)a;
      float s  =  c0 * sw1[k] + c1 * sw1[16 + k] + c2 * sw1[32 + k];
      float sb = -c0 * sw1[k] + c1 * sw1[16 + k] + c2 * sw1[32 + k];
      APre[row * 32 + 16 + k] = (_Float16)(s + sb1[k]);
      BPre[row * 32 + 16 + k] = (_Float16)sb;
    }
  }
}

// ---------------------------------------------------------------------------
// qkv_gemm: x f32 read directly (cast in-flight); epilogues via per-wave LDS
// transpose -> coalesced 16B stores (round 8/9 version, kept).
// ---------------------------------------------------------------------------
__global__ __launch_bounds__(256) void qkv_gemm(
    const float* __restrict__ x, const _Float16* __restrict__ WqkvT,
    _Float16* __restrict__ Qh, _Float16* __restrict__ Kh,
    _Float16* __restrict__ Vt)
{
  __shared__ __align__(16) _Float16 tbuf[4][1536];
  const int wv = threadIdx.x >> 6;
  const int wg = blockIdx.x * 4 + wv;
  const int ti = wg / 12, og = wg % 12;
  const int i0 = ti * 16, o0 = og * 64;
  const int lane = threadIdx.x & 63, q = lane >> 4, c = lane & 15;
  f32x4 acc[4] = {{0,0,0,0},{0,0,0,0},{0,0,0,0},{0,0,0,0}};
  const float*    arow = x + (i0 + c) * 256;
  const _Float16* brow = WqkvT + (o0 + c) * 256;
#pragma unroll
  for (int k0 = 0; k0 < 256; k0 += 32) {
    f32x4 a0 = *reinterpret_cast<const f32x4*>(arow + k0 + q * 8);
    f32x4 a1 = *reinterpret_cast<const f32x4*>(arow + k0 + q * 8 + 4);
    half8_t af;
    af[0] = (_Float16)a0[0]; af[1] = (_Float16)a0[1];
    af[2] = (_Float16)a0[2]; af[3] = (_Float16)a0[3];
    af[4] = (_Float16)a1[0]; af[5] = (_Float16)a1[1];
    af[6] = (_Float16)a1[2]; af[7] = (_Float16)a1[3];
#pragma unroll
    for (int t = 0; t < 4; ++t) {
      half8_t bf = *reinterpret_cast<const half8_t*>(brow + t * 16 * 256 + k0 + q * 8);
      acc[t] = __builtin_amdgcn_mfma_f32_16x16x32_f16(af, bf, acc[t], 0, 0, 0);
    }
  }
  const int b = i0 >> 11, n0 = i0 & 2047;
  _Float16* vt = tbuf[wv];
  if (og < 8) {                          // Q / K epilogue via LDS transpose
#pragma unroll
    for (int t = 0; t < 4; ++t)
#pragma unroll
      for (int r = 0; r < 4; ++r)
        vt[(q * 4 + r) * 72 + t * 16 + c] = (_Float16)acc[t][r];
    asm volatile("s_waitcnt lgkmcnt(0)" ::: "memory");   // wave-private tile
    __builtin_amdgcn_sched_barrier(0);
    const int nl = lane & 15, seg = lane >> 4;
    const int o_g = o0 + seg * 16;                 // wave-uniform Q-vs-K split
    const int h = (o_g >> 5) & 7, dbase = o_g & 31;
    _Float16* dst = ((o_g >> 8) == 0 ? Qh : Kh) +
                    ((b * 8 + h) * 2048 + n0 + nl) * 32 + dbase;
    half8_t r0 = *reinterpret_cast<const half8_t*>(vt + nl * 72 + seg * 16);
    half8_t r1 = *reinterpret_cast<const half8_t*>(vt + nl * 72 + seg * 16 + 8);
    *reinterpret_cast<half8_t*>(dst)     = r0;
    *reinterpret_cast<half8_t*>(dst + 8) = r1;
  } else {                               // V epilogue via LDS transpose
#pragma unroll
    for (int t = 0; t < 4; ++t)
#pragma unroll
      for (int r = 0; r < 4; ++r)
        vt[(t * 16 + c) * 24 + q * 4 + r] = (_Float16)acc[t][r];
    asm volatile("s_waitcnt lgkmcnt(0)" ::: "memory");
    __builtin_amdgcn_sched_barrier(0);
    const long row = (long)(b * 256 + (o0 - 512) + lane);
    half8_t r0 = *reinterpret_cast<const half8_t*>(vt + lane * 24);
    half8_t r1 = *reinterpret_cast<const half8_t*>(vt + lane * 24 + 8);
    *reinterpret_cast<half8_t*>(Vt + row * 2048 + n0)     = r0;
    *reinterpret_cast<half8_t*>(Vt + row * 2048 + n0 + 8) = r1;
  }
}

// ---------------------------------------------------------------------------
// flash: EXACT round-10 version (best measured: 60.2 µs, VGPR 64, no spill).
// r11 (prod/consume decoupling) was null; r12 (K/V prefetch + reordered
// bias_prod) spilled (WRITE 9.7->79.7 MB at pinned VGPR 64). Converged:
//   - (512,4) mandatory; (512,6) spills (r4, unified VGPR/AGPR file).
//   - KVBLK=64 pair unroll spills (r6); K/V reg-prefetch spills (r12).
//   - occupancy not the lever (r5 nck=8 null); barrier reorder null (r11).
// Structure: two 16-row Q streams A/B; per tile: bias-prod -> scores ->
// barrier -> softmax (bbm fold, defer-max lane-local trigger) -> pbuf
// fence -> PV + lp ones-MFMA; bpf prefetched one tile ahead (r10 win).
// ---------------------------------------------------------------------------
__global__ __launch_bounds__(512, 4) void flash(
    const _Float16* __restrict__ Qh, const _Float16* __restrict__ Kh,
    const _Float16* __restrict__ Vt, const _Float16* __restrict__ APre,
    const _Float16* __restrict__ BPre, const float* __restrict__ pw2,
    const float* __restrict__ sw2, _Float16* __restrict__ Opart,
    float* __restrict__ Mpart)
{
  __shared__ __align__(16) unsigned char smem[53504];
  _Float16* biasH = reinterpret_cast<_Float16*>(smem);          // [2][8h*1160] f16
  _Float16* pbuf  = reinterpret_cast<_Float16*>(smem + 37120);  // [8w][2][16 x 32] f16

  const int blk = blockIdx.x;
  const int b     = blk >> 8;
  const int chunk = (blk >> 6) & 3;
  const int i0    = (blk & 63) << 5;
  const int tid = threadIdx.x;
  const int w = tid >> 6, lane = tid & 63;
  const int q = lane >> 4, c = lane & 15;

  // Q fragments (A-operand): stream A rows i0+c, stream B rows i0+16+c
  const _Float16* qbase = Qh + ((b * 8 + w) * 2048 + i0) * 32;
  half8_t qfA = *reinterpret_cast<const half8_t*>(qbase + c * 32 + q * 8);
  half8_t qfB = *reinterpret_cast<const half8_t*>(qbase + (16 + c) * 32 + q * 8);
  // APre fragments for bias-MFMA A side, j-invariant
  const _Float16* abase = APre + (b * 2048 + i0) * 32;
  half8_t apfA = *reinterpret_cast<const half8_t*>(abase + c * 32 + q * 8);
  half8_t apfB = *reinterpret_cast<const half8_t*>(abase + (16 + c) * 32 + q * 8);

  // stacked W2 B-fragment: B[k][n], k<16 -> pos_w2, k>=16 -> sym_w2; *LOG2E
  half8_t w2f;
#pragma unroll
  for (int jj = 0; jj < 8; ++jj) {
    const int k = q * 8 + jj;
    float val = 0.f;
    if (c < 8) val = (k < 16 ? pw2[k * 8 + c] : sw2[(k - 16) * 8 + c]) * LOG2E;
    w2f[jj] = (_Float16)val;
  }
  half8_t ones8;
#pragma unroll
  for (int jj = 0; jj < 8; ++jj) ones8[jj] = (_Float16)1.0f;

  float mA[4], mB[4];
  f32x4 O0A = {0,0,0,0}, O1A = {0,0,0,0}, O0B = {0,0,0,0}, O1B = {0,0,0,0};
  f32x4 lpA = {0,0,0,0}, lpB = {0,0,0,0};
#pragma unroll
  for (int r = 0; r < 4; ++r) { mA[r] = 0.f; mB[r] = 0.f; }  // m init 0 (exact)

  const f32x4 z4 = {0.f, 0.f, 0.f, 0.f};
  half8_t hzero8 = {};

  const int jbase = chunk * 512;
  const _Float16* BPre_b = BPre + (long)b * 2048 * 32;

  // ---- hoisted per-lane bases/offsets ----
  const int bwoff = c * 1160 + w * 144 + q * 4;   // bias write: + mt*36 (+16 B-half)
  const int broff = w * 1160 + c * 72 + q * 4;    // bias read: +0,+36,+16,+52
  _Float16* pbA = pbuf + w * 1024;
  _Float16* pbB = pbA + 512;
  const int pwo = q * 128 + 2 * c;                // pbuf write: + r*32
  const int pro = c * 32 + q * 8;                 // pbuf read
  const _Float16* kb0 = Kh + ((b * 8 + w) * 2048 + jbase) * 32;
  const _Float16* vb0 = Vt + (b * 8 + w) * 65536 + jbase;
  const int ko0 = (2 * c) * 32 + q * 8, ko1 = ko0 + 32;
  const int vo0 = c * 2048 + q * 8,     vo1 = vo0 + 16 * 2048;
  const _Float16* bpb = BPre_b + (jbase + w * 4) * 32 + q * 8;

  // ---- prefetch tile-0 BPre ----
  half8_t pf0 = *reinterpret_cast<const half8_t*>(bpb);
  half8_t pf1 = *reinterpret_cast<const half8_t*>(bpb + 32);
  half8_t pf2 = *reinterpret_cast<const half8_t*>(bpb + 64);
  half8_t pf3 = *reinterpret_cast<const half8_t*>(bpb + 96);

  auto tile = [&](const int jt, _Float16* bH) {
    // ---- bias for this tile (bpf prefetched last iteration) ----
    _Float16* bW = bH + bwoff;
#pragma unroll
    for (int mt = 0; mt < 4; ++mt) {
      half8_t bpf = (mt == 0) ? pf0 : (mt == 1) ? pf1 : (mt == 2) ? pf2 : pf3;
      half8_t hvA = __builtin_elementwise_max(apfA - bpf, hzero8);
      f32x4 bcA = __builtin_amdgcn_mfma_f32_16x16x32_f16(hvA, w2f, z4, 0, 0, 0);
      half8_t hvB = __builtin_elementwise_max(apfB - bpf, hzero8);
      f32x4 bcB = __builtin_amdgcn_mfma_f32_16x16x32_f16(hvB, w2f, z4, 0, 0, 0);
      if (c < 8) {   // [h=c][j=w*4+mt][i], j-stride 36, h-stride 1160
        half4_t b4;
        b4[0] = (_Float16)bcA[0]; b4[1] = (_Float16)bcA[1];
        b4[2] = (_Float16)bcA[2]; b4[3] = (_Float16)bcA[3];
        *reinterpret_cast<half4_t*>(bW + mt * 36) = b4;
        half4_t b5;
        b5[0] = (_Float16)bcB[0]; b5[1] = (_Float16)bcB[1];
        b5[2] = (_Float16)bcB[2]; b5[3] = (_Float16)bcB[3];
        *reinterpret_cast<half4_t*>(bW + mt * 36 + 16) = b5;
      }
    }

    // ---- K/V fragments; scores ----
    const _Float16* kbase = kb0 + jt * 1024;
    const _Float16* vbase = vb0 + jt * 32;
    half8_t kf0 = *reinterpret_cast<const half8_t*>(kbase + ko0);
    half8_t kf1 = *reinterpret_cast<const half8_t*>(kbase + ko1);
    half8_t vf0 = *reinterpret_cast<const half8_t*>(vbase + vo0);
    half8_t vf1 = *reinterpret_cast<const half8_t*>(vbase + vo1);
    f32x4 sA0 = __builtin_amdgcn_mfma_f32_16x16x32_f16(qfA, kf0, z4, 0, 0, 0);
    f32x4 sA1 = __builtin_amdgcn_mfma_f32_16x16x32_f16(qfA, kf1, z4, 0, 0, 0);
    f32x4 sB0 = __builtin_amdgcn_mfma_f32_16x16x32_f16(qfB, kf0, z4, 0, 0, 0);
    f32x4 sB1 = __builtin_amdgcn_mfma_f32_16x16x32_f16(qfB, kf1, z4, 0, 0, 0);

    // ---- prefetch next tile's BPre (consumed next iteration) ----
    {
      const _Float16* bp = bpb + ((jt < 15) ? (jt + 1) : jt) * 1024;
      pf0 = *reinterpret_cast<const half8_t*>(bp);
      pf1 = *reinterpret_cast<const half8_t*>(bp + 32);
      pf2 = *reinterpret_cast<const half8_t*>(bp + 64);
      pf3 = *reinterpret_cast<const half8_t*>(bp + 96);
    }

    __syncthreads();   // bias[this tile] visible (sole barrier)

    const _Float16* bR = bH + broff;
    half4_t bbA0 = *reinterpret_cast<const half4_t*>(bR);
    half4_t bbA1 = *reinterpret_cast<const half4_t*>(bR + 36);
    half4_t bbB0 = *reinterpret_cast<const half4_t*>(bR + 16);
    half4_t bbB1 = *reinterpret_cast<const half4_t*>(bR + 52);

    // ---- stream A online softmax (bbm fold: svm = s*KSCALE + (bias-m)) ----
    {
      float svm0[4], svm1[4], p0[4], p1[4];
#pragma unroll
      for (int r = 0; r < 4; ++r) {
        const float bm0 = (float)bbA0[r] - mA[r];
        const float bm1 = (float)bbA1[r] - mA[r];
        svm0[r] = fmaf(sA0[r], KSCALE, bm0);
        svm1[r] = fmaf(sA1[r], KSCALE, bm1);
        p0[r] = EXP2F(svm0[r]);
        p1[r] = EXP2F(svm1[r]);
      }
      float need = fmaxf(fmaxf(fmaxf(svm0[0], svm1[0]), fmaxf(svm0[1], svm1[1])),
                         fmaxf(fmaxf(svm0[2], svm1[2]), fmaxf(svm0[3], svm1[3])));
      if (__any(need > 4.0f)) {   // rare: full row reduce + rescale + p-fix
        float mr[4];
#pragma unroll
        for (int r = 0; r < 4; ++r) mr[r] = fmaxf(svm0[r], svm1[r]) + mA[r];
        h2 pk01, pk23;
        pk01[0] = (_Float16)mr[0]; pk01[1] = (_Float16)mr[1];
        pk23[0] = (_Float16)mr[2]; pk23[1] = (_Float16)mr[3];
        pk01 = rowmax16_h2(pk01);
        pk23 = rowmax16_h2(pk23);
        float mred[4] = {(float)pk01[0], (float)pk01[1],
                         (float)pk23[0], (float)pk23[1]};
#pragma unroll
        for (int r = 0; r < 4; ++r) {
          const float mnew = fmaxf(mA[r], mred[r]);
          const float alpha = EXP2F(mA[r] - mnew);
          p0[r] *= alpha; p1[r] *= alpha;
          lpA[r] *= alpha;
          O0A[r] *= alpha; O1A[r] *= alpha;
          mA[r] = mnew;
        }
      }
#pragma unroll
      for (int r = 0; r < 4; ++r) {
        h2 pp; pp[0] = (_Float16)p0[r]; pp[1] = (_Float16)p1[r];
        *reinterpret_cast<h2*>(pbA + pwo + r * 32) = pp;
      }
    }
    // ---- stream B ----
    {
      float svm0[4], svm1[4], p0[4], p1[4];
#pragma unroll
      for (int r = 0; r < 4; ++r) {
        const float bm0 = (float)bbB0[r] - mB[r];
        const float bm1 = (float)bbB1[r] - mB[r];
        svm0[r] = fmaf(sB0[r], KSCALE, bm0);
        svm1[r] = fmaf(sB1[r], KSCALE, bm1);
        p0[r] = EXP2F(svm0[r]);
        p1[r] = EXP2F(svm1[r]);
      }
      float need = fmaxf(fmaxf(fmaxf(svm0[0], svm1[0]), fmaxf(svm0[1], svm1[1])),
                         fmaxf(fmaxf(svm0[2], svm1[2]), fmaxf(svm0[3], svm1[3])));
      if (__any(need > 4.0f)) {
        float mr[4];
#pragma unroll
        for (int r = 0; r < 4; ++r) mr[r] = fmaxf(svm0[r], svm1[r]) + mB[r];
        h2 pk01, pk23;
        pk01[0] = (_Float16)mr[0]; pk01[1] = (_Float16)mr[1];
        pk23[0] = (_Float16)mr[2]; pk23[1] = (_Float16)mr[3];
        pk01 = rowmax16_h2(pk01);
        pk23 = rowmax16_h2(pk23);
        float mred[4] = {(float)pk01[0], (float)pk01[1],
                         (float)pk23[0], (float)pk23[1]};
#pragma unroll
        for (int r = 0; r < 4; ++r) {
          const float mnew = fmaxf(mB[r], mred[r]);
          const float alpha = EXP2F(mB[r] - mnew);
          p0[r] *= alpha; p1[r] *= alpha;
          lpB[r] *= alpha;
          O0B[r] *= alpha; O1B[r] *= alpha;
          mB[r] = mnew;
        }
      }
#pragma unroll
      for (int r = 0; r < 4; ++r) {
        h2 pp; pp[0] = (_Float16)p0[r]; pp[1] = (_Float16)p1[r];
        *reinterpret_cast<h2*>(pbB + pwo + r * 32) = pp;
      }
    }

    // wave-private pbuf: order writes before reads (LDS only — no vmcnt drain)
    asm volatile("s_waitcnt lgkmcnt(0)" ::: "memory");
    __builtin_amdgcn_sched_barrier(0);

    half8_t pfAx = *reinterpret_cast<const half8_t*>(pbA + pro);
    half8_t pfBx = *reinterpret_cast<const half8_t*>(pbB + pro);
    O0A = __builtin_amdgcn_mfma_f32_16x16x32_f16(pfAx, vf0, O0A, 0, 0, 0);
    O1A = __builtin_amdgcn_mfma_f32_16x16x32_f16(pfAx, vf1, O1A, 0, 0, 0);
    O0B = __builtin_amdgcn_mfma_f32_16x16x32_f16(pfBx, vf0, O0B, 0, 0, 0);
    O1B = __builtin_amdgcn_mfma_f32_16x16x32_f16(pfBx, vf1, O1B, 0, 0, 0);
    lpA = __builtin_amdgcn_mfma_f32_16x16x32_f16(pfAx, ones8, lpA, 0, 0, 0);
    lpB = __builtin_amdgcn_mfma_f32_16x16x32_f16(pfBx, ones8, lpB, 0, 0, 0);
  };

  // unroll-by-2: dbuf halves are compile-time per call site
  for (int pt = 0; pt < 8; ++pt) {
    tile(2 * pt,     biasH);
    tile(2 * pt + 1, biasH + 9280);
  }

  // ---- finalize: lp already full row sums (ones-MFMA); no lane reduce ----
#pragma unroll
  for (int r = 0; r < 4; ++r) {
    const float s = lpA[r];
    const float inv = 1.f / s;
    const int n = i0 + q * 4 + r;
    const long base = (long)(((chunk * 2 + b) * 8 + w) * 2048 + n);
    Opart[base * 32 + c]      = (_Float16)(O0A[r] * inv);
    Opart[base * 32 + 16 + c] = (_Float16)(O1A[r] * inv);
    if (c == 0) Mpart[base] = mA[r] + __log2f(s);
  }
#pragma unroll
  for (int r = 0; r < 4; ++r) {
    const float s = lpB[r];
    const float inv = 1.f / s;
    const int n = i0 + 16 + q * 4 + r;
    const long base = (long)(((chunk * 2 + b) * 8 + w) * 2048 + n);
    Opart[base * 32 + c]      = (_Float16)(O0B[r] * inv);
    Opart[base * 32 + 16 + c] = (_Float16)(O1B[r] * inv);
    if (c == 0) Mpart[base] = mB[r] + __log2f(s);
  }
}

// ---------------------------------------------------------------------------
// combine_proj: fused merge of 4 j-chunk partials -> LDS -> proj GEMM.
// ---------------------------------------------------------------------------
__global__ __launch_bounds__(256) void combine_proj(
    const _Float16* __restrict__ Opart, const float* __restrict__ Mpart,
    const _Float16* __restrict__ WoutT, const float* __restrict__ bout,
    float* __restrict__ out)
{
  __shared__ _Float16 aT[16][264];   // 16 rows x 256 cols, +8 pad
  const int i0 = blockIdx.x * 16;    // global row in [0,4096)
  const int b = i0 >> 11;
  const int n0 = i0 & 2047;
  const int tid = threadIdx.x;
  {
    const int row = tid >> 4, cg = tid & 15;   // col group: cols cg*16..+15
    const int n = n0 + row;
    const int h = cg >> 1;
    const int d0 = (cg & 1) * 16;
    float mv[4], M = -INFINITY;
#pragma unroll
    for (int ck = 0; ck < 4; ++ck) {
      mv[ck] = Mpart[((ck * 2 + b) * 8 + h) * 2048 + n];
      M = fmaxf(M, mv[ck]);
    }
    float num[16];
#pragma unroll
    for (int e = 0; e < 16; ++e) num[e] = 0.f;
    float den = 0.f;
#pragma unroll
    for (int ck = 0; ck < 4; ++ck) {
      const float wgt = EXP2F(mv[ck] - M);
      const _Float16* op = Opart +
          (long)(((ck * 2 + b) * 8 + h) * 2048 + n) * 32 + d0;
      half8_t o0v = *reinterpret_cast<const half8_t*>(op);
      half8_t o1v = *reinterpret_cast<const half8_t*>(op + 8);
#pragma unroll
      for (int e = 0; e < 8; ++e) {
        num[e]     += wgt * (float)o0v[e];
        num[8 + e] += wgt * (float)o1v[e];
      }
      den += wgt;
    }
    const float inv = 1.f / den;
    half8_t h0, h1;
#pragma unroll
    for (int e = 0; e < 8; ++e) {
      h0[e] = (_Float16)(num[e] * inv);
      h1[e] = (_Float16)(num[8 + e] * inv);
    }
    *reinterpret_cast<half8_t*>(&aT[row][cg * 16])     = h0;
    *reinterpret_cast<half8_t*>(&aT[row][cg * 16 + 8]) = h1;
  }
  __syncthreads();

  // ---- proj GEMM: wave does 16i x 64o (4 tiles), A from LDS ----
  const int o0 = (tid >> 6) * 64;
  const int lane = tid & 63, q = lane >> 4, c = lane & 15;
  f32x4 acc[4] = {{0,0,0,0},{0,0,0,0},{0,0,0,0},{0,0,0,0}};
  const _Float16* brow = WoutT + (o0 + c) * 256;
#pragma unroll
  for (int k0 = 0; k0 < 256; k0 += 32) {
    half8_t af = *reinterpret_cast<const half8_t*>(&aT[c][k0 + q * 8]);
#pragma unroll
    for (int t = 0; t < 4; ++t) {
      half8_t bf = *reinterpret_cast<const half8_t*>(brow + t * 16 * 256 + k0 + q * 8);
      acc[t] = __builtin_amdgcn_mfma_f32_16x16x32_f16(af, bf, acc[t], 0, 0, 0);
    }
  }
#pragma unroll
  for (int t = 0; t < 4; ++t) {
    const float bo = bout[o0 + t * 16 + c];
#pragma unroll
    for (int r = 0; r < 4; ++r)
      out[(i0 + q * 4 + r) * 256 + o0 + t * 16 + c] = acc[t][r] + bo;
  }
}

// ---------------------------------------------------------------------------
extern "C" void kernel_launch(void* const* d_in, const int* in_sizes, int n_in,
                              void* d_out, int out_size, void* d_ws, size_t ws_size,
                              hipStream_t stream)
{
  const float* x      = (const float*)d_in[0];
  const float* coords = (const float*)d_in[1];
  const float* Wqkv   = (const float*)d_in[2];
  const float* Wout   = (const float*)d_in[3];
  const float* bout   = (const float*)d_in[4];
  const float* pw1    = (const float*)d_in[5];
  const float* pb1    = (const float*)d_in[6];
  const float* pw2    = (const float*)d_in[7];
  const float* sw1    = (const float*)d_in[9];
  const float* sb1    = (const float*)d_in[10];
  const float* sw2    = (const float*)d_in[11];
  float* out = (float*)d_out;

  char* ws = (char*)d_ws;
  _Float16* Qh      = (_Float16*)(ws + 0);         // 2 MB
  _Float16* Kh      = (_Float16*)(ws + 2097152);   // 2 MB
  _Float16* Vt      = (_Float16*)(ws + 4194304);   // 2 MB
  _Float16* WqkvT   = (_Float16*)(ws + 8388608);   // 384 KB
  _Float16* WoutT   = (_Float16*)(ws + 8781824);   // 128 KB
  _Float16* APre    = (_Float16*)(ws + 8912896);   // 256 KB
  _Float16* BPre    = (_Float16*)(ws + 9175040);   // 256 KB
  _Float16* Opart   = (_Float16*)(ws + 9437184);   // 8 MB  [4][2][8][2048][32]
  float*    Mpart   = (float*)   (ws + 17825792);  // 512 KB [4][2][8][2048]

  prep_misc<<<80, 256, 0, stream>>>(Wqkv, Wout, coords, pw1, pb1, sw1, sb1,
                                    WqkvT, WoutT, APre, BPre);
  qkv_gemm<<<768, 256, 0, stream>>>(x, WqkvT, Qh, Kh, Vt);
  flash<<<512, 512, 0, stream>>>(Qh, Kh, Vt, APre, BPre, pw2, sw2, Opart, Mpart);
  combine_proj<<<256, 256, 0, stream>>>(Opart, Mpart, WoutT, bout, out);
}

// Round 14
// 156.827 us; speedup vs baseline: 1.2940x; 1.0005x over previous
//
#include <hip/hip_runtime.h>
#include <hip/hip_fp16.h>

// ---------------- types ----------------
typedef _Float16 half8_t __attribute__((ext_vector_type(8)));
typedef _Float16 half4_t __attribute__((ext_vector_type(4)));
typedef _Float16 h2      __attribute__((ext_vector_type(2)));
typedef float    f32x4   __attribute__((ext_vector_type(4)));

#define LOG2E 1.4426950408889634f
// SCALE = 1/sqrt(32); fold log2(e) so we can use exp2
#define KSCALE (0.17677669529663687f * LOG2E)

#if __has_builtin(__builtin_amdgcn_exp2f)
#define EXP2F(x) __builtin_amdgcn_exp2f(x)
#else
#define EXP2F(x) exp2f(x)
#endif

// DPP row_ror:N (rotate within 16-lane row) — VALU cross-lane, no LDS pipe.
template <int N>
__device__ __forceinline__ int dpp_ror(int v) {
  return __builtin_amdgcn_update_dpp(0, v, 0x120 + N, 0xf, 0xf, true);
}
// 16-lane max-reduce of two independent f16 values packed in h2.
__device__ __forceinline__ h2 rowmax16_h2(h2 v) {
  int t;
  t = dpp_ror<1>(__builtin_bit_cast(int, v));
  v = __builtin_elementwise_max(v, __builtin_bit_cast(h2, t));
  t = dpp_ror<2>(__builtin_bit_cast(int, v));
  v = __builtin_elementwise_max(v, __builtin_bit_cast(h2, t));
  t = dpp_ror<4>(__builtin_bit_cast(int, v));
  v = __builtin_elementwise_max(v, __builtin_bit_cast(h2, t));
  t = dpp_ror<8>(__builtin_bit_cast(int, v));
  v = __builtin_elementwise_max(v, __builtin_bit_cast(h2, t));
  return v;
}

// ---------------------------------------------------------------------------
// prep: [0,48)  Wqkv^T via LDS 64x64 tile transpose; [48,64) Wout^T;
//       [64,80) coords layer-1 precompute
// ---------------------------------------------------------------------------
__global__ __launch_bounds__(256) void prep_misc(
    const float* __restrict__ Wqkv, const float* __restrict__ Wout,
    const float* __restrict__ coords,
    const float* __restrict__ pw1, const float* __restrict__ pb1,
    const float* __restrict__ sw1, const float* __restrict__ sb1,
    _Float16* __restrict__ WqkvT, _Float16* __restrict__ WoutT,
    _Float16* __restrict__ APre, _Float16* __restrict__ BPre)
{
  __shared__ float tile[64][65];
  const int bi = blockIdx.x, tid = threadIdx.x;
  if (bi < 64) {                         // W transposes, 64x64 tiles
    const float* src; _Float16* dst; int t, W;  // W = src row width
    if (bi < 48) { t = bi;      src = Wqkv; dst = WqkvT; W = 768; }
    else         { t = bi - 48; src = Wout; dst = WoutT; W = 256; }
    const int nOT = W >> 6;              // o-tiles per k-row
    const int tk = t / nOT, to = t % nOT;
    const int cx = tid & 63, ry = tid >> 6;
#pragma unroll
    for (int rr = 0; rr < 16; ++rr) {
      const int kl = rr * 4 + ry;
      tile[kl][cx] = src[(tk * 64 + kl) * W + to * 64 + cx];
    }
    __syncthreads();
#pragma unroll
    for (int rr = 0; rr < 16; ++rr) {
      const int ol = rr * 4 + ry;
      dst[(to * 64 + ol) * 256 + tk * 64 + cx] = (_Float16)tile[cx][ol];
    }
  } else {                               // coords precompute: 4096 rows
    const int row = (bi - 64) * 256 + tid;
    const float c0 = coords[row * 3 + 0];
    const float c1 = coords[row * 3 + 1];
    const float c2 = coords[row * 3 + 2];
#pragma unroll
    for (int k = 0; k < 16; ++k) {
      float a = c0 * pw1[k] + c1 * pw1[16 + k] + c2 * pw1[32 + k];
      APre[row * 32 + k] = (_Float16)(a + pb1[k]);
      BPre[row * 32 + k] = (_Float16)a;
      float s  =  c0 * sw1[k] + c1 * sw1[16 + k] + c2 * sw1[32 + k];
      float sb = -c0 * sw1[k] + c1 * sw1[16 + k] + c2 * sw1[32 + k];
      APre[row * 32 + 16 + k] = (_Float16)(s + sb1[k]);
      BPre[row * 32 + 16 + k] = (_Float16)sb;
    }
  }
}

// ---------------------------------------------------------------------------
// qkv_gemm: x f32 read directly (cast in-flight); epilogues via per-wave LDS
// transpose -> coalesced 16B stores (round 8/9 version, kept).
// ---------------------------------------------------------------------------
__global__ __launch_bounds__(256) void qkv_gemm(
    const float* __restrict__ x, const _Float16* __restrict__ WqkvT,
    _Float16* __restrict__ Qh, _Float16* __restrict__ Kh,
    _Float16* __restrict__ Vt)
{
  __shared__ __align__(16) _Float16 tbuf[4][1536];
  const int wv = threadIdx.x >> 6;
  const int wg = blockIdx.x * 4 + wv;
  const int ti = wg / 12, og = wg % 12;
  const int i0 = ti * 16, o0 = og * 64;
  const int lane = threadIdx.x & 63, q = lane >> 4, c = lane & 15;
  f32x4 acc[4] = {{0,0,0,0},{0,0,0,0},{0,0,0,0},{0,0,0,0}};
  const float*    arow = x + (i0 + c) * 256;
  const _Float16* brow = WqkvT + (o0 + c) * 256;
#pragma unroll
  for (int k0 = 0; k0 < 256; k0 += 32) {
    f32x4 a0 = *reinterpret_cast<const f32x4*>(arow + k0 + q * 8);
    f32x4 a1 = *reinterpret_cast<const f32x4*>(arow + k0 + q * 8 + 4);
    half8_t af;
    af[0] = (_Float16)a0[0]; af[1] = (_Float16)a0[1];
    af[2] = (_Float16)a0[2]; af[3] = (_Float16)a0[3];
    af[4] = (_Float16)a1[0]; af[5] = (_Float16)a1[1];
    af[6] = (_Float16)a1[2]; af[7] = (_Float16)a1[3];
#pragma unroll
    for (int t = 0; t < 4; ++t) {
      half8_t bf = *reinterpret_cast<const half8_t*>(brow + t * 16 * 256 + k0 + q * 8);
      acc[t] = __builtin_amdgcn_mfma_f32_16x16x32_f16(af, bf, acc[t], 0, 0, 0);
    }
  }
  const int b = i0 >> 11, n0 = i0 & 2047;
  _Float16* vt = tbuf[wv];
  if (og < 8) {                          // Q / K epilogue via LDS transpose
#pragma unroll
    for (int t = 0; t < 4; ++t)
#pragma unroll
      for (int r = 0; r < 4; ++r)
        vt[(q * 4 + r) * 72 + t * 16 + c] = (_Float16)acc[t][r];
    asm volatile("s_waitcnt lgkmcnt(0)" ::: "memory");   // wave-private tile
    __builtin_amdgcn_sched_barrier(0);
    const int nl = lane & 15, seg = lane >> 4;
    const int o_g = o0 + seg * 16;                 // wave-uniform Q-vs-K split
    const int h = (o_g >> 5) & 7, dbase = o_g & 31;
    _Float16* dst = ((o_g >> 8) == 0 ? Qh : Kh) +
                    ((b * 8 + h) * 2048 + n0 + nl) * 32 + dbase;
    half8_t r0 = *reinterpret_cast<const half8_t*>(vt + nl * 72 + seg * 16);
    half8_t r1 = *reinterpret_cast<const half8_t*>(vt + nl * 72 + seg * 16 + 8);
    *reinterpret_cast<half8_t*>(dst)     = r0;
    *reinterpret_cast<half8_t*>(dst + 8) = r1;
  } else {                               // V epilogue via LDS transpose
#pragma unroll
    for (int t = 0; t < 4; ++t)
#pragma unroll
      for (int r = 0; r < 4; ++r)
        vt[(t * 16 + c) * 24 + q * 4 + r] = (_Float16)acc[t][r];
    asm volatile("s_waitcnt lgkmcnt(0)" ::: "memory");
    __builtin_amdgcn_sched_barrier(0);
    const long row = (long)(b * 256 + (o0 - 512) + lane);
    half8_t r0 = *reinterpret_cast<const half8_t*>(vt + lane * 24);
    half8_t r1 = *reinterpret_cast<const half8_t*>(vt + lane * 24 + 8);
    *reinterpret_cast<half8_t*>(Vt + row * 2048 + n0)     = r0;
    *reinterpret_cast<half8_t*>(Vt + row * 2048 + n0 + 8) = r1;
  }
}

// ---------------------------------------------------------------------------
// flash: r13 body (best: 54.9 µs) with two register-neutral micro-changes:
//   * P stored to pbuf BEFORE the rescale-trigger branch — the 8 stores no
//     longer wait on the 7-op serial max chain + s_cbranch; rare branch
//     rescales p and RE-stores (exact).
//   * bias j-entry interleaved [q*8:A4|B4] (stride 36 kept): j=2c read is
//     one aligned ds_read_b128 (A0|B0); j=2c+1 stays two half4 reads.
//     Banks: 4c%32 distinct c<8, 2-way c>=8 (free, m136); writes unchanged
//     count. 4 bias reads -> 3 per wave-tile.
// Converged constraints: (512,4) mandatory ((512,6) spills r4); KVBLK=64
// spills (r6); K/V reg-prefetch spills (r12); occupancy null (r5); barrier
// reorder null (r11). bpf prefetch one tile ahead = r10 win, kept.
// ---------------------------------------------------------------------------
__global__ __launch_bounds__(512, 4) void flash(
    const _Float16* __restrict__ Qh, const _Float16* __restrict__ Kh,
    const _Float16* __restrict__ Vt, const _Float16* __restrict__ APre,
    const _Float16* __restrict__ BPre, const float* __restrict__ pw2,
    const float* __restrict__ sw2, _Float16* __restrict__ Opart,
    float* __restrict__ Mpart)
{
  __shared__ __align__(16) unsigned char smem[53504];
  _Float16* biasH = reinterpret_cast<_Float16*>(smem);          // [2][8h*1160] f16
  _Float16* pbuf  = reinterpret_cast<_Float16*>(smem + 37120);  // [8w][2][16 x 32] f16

  const int blk = blockIdx.x;
  const int b     = blk >> 8;
  const int chunk = (blk >> 6) & 3;
  const int i0    = (blk & 63) << 5;
  const int tid = threadIdx.x;
  const int w = tid >> 6, lane = tid & 63;
  const int q = lane >> 4, c = lane & 15;

  // Q fragments (A-operand): stream A rows i0+c, stream B rows i0+16+c
  const _Float16* qbase = Qh + ((b * 8 + w) * 2048 + i0) * 32;
  half8_t qfA = *reinterpret_cast<const half8_t*>(qbase + c * 32 + q * 8);
  half8_t qfB = *reinterpret_cast<const half8_t*>(qbase + (16 + c) * 32 + q * 8);
  // APre fragments for bias-MFMA A side, j-invariant
  const _Float16* abase = APre + (b * 2048 + i0) * 32;
  half8_t apfA = *reinterpret_cast<const half8_t*>(abase + c * 32 + q * 8);
  half8_t apfB = *reinterpret_cast<const half8_t*>(abase + (16 + c) * 32 + q * 8);

  // stacked W2 B-fragment: B[k][n], k<16 -> pos_w2, k>=16 -> sym_w2; *LOG2E
  half8_t w2f;
#pragma unroll
  for (int jj = 0; jj < 8; ++jj) {
    const int k = q * 8 + jj;
    float val = 0.f;
    if (c < 8) val = (k < 16 ? pw2[k * 8 + c] : sw2[(k - 16) * 8 + c]) * LOG2E;
    w2f[jj] = (_Float16)val;
  }
  half8_t ones8;
#pragma unroll
  for (int jj = 0; jj < 8; ++jj) ones8[jj] = (_Float16)1.0f;

  float mA[4], mB[4];
  f32x4 O0A = {0,0,0,0}, O1A = {0,0,0,0}, O0B = {0,0,0,0}, O1B = {0,0,0,0};
  f32x4 lpA = {0,0,0,0}, lpB = {0,0,0,0};
#pragma unroll
  for (int r = 0; r < 4; ++r) { mA[r] = 0.f; mB[r] = 0.f; }  // m init 0 (exact)

  const f32x4 z4 = {0.f, 0.f, 0.f, 0.f};
  half8_t hzero8 = {};

  const int jbase = chunk * 512;
  const _Float16* BPre_b = BPre + (long)b * 2048 * 32;

  // ---- hoisted per-lane bases/offsets ----
  // bias entry (36 halves/j): [q*8 + 0..3] = stream-A rows, [q*8 + 4..7] = B
  const int bwoff = c * 1160 + w * 144 + q * 8;   // bias write: + mt*36 (A), +4 (B)
  const int broff = w * 1160 + c * 72 + q * 8;    // bias read: b128 @0; +36,+40
  _Float16* pbA = pbuf + w * 1024;
  _Float16* pbB = pbA + 512;
  const int pwo = q * 128 + 2 * c;                // pbuf write: + r*32
  const int pro = c * 32 + q * 8;                 // pbuf read
  const _Float16* kb0 = Kh + ((b * 8 + w) * 2048 + jbase) * 32;
  const _Float16* vb0 = Vt + (b * 8 + w) * 65536 + jbase;
  const int ko0 = (2 * c) * 32 + q * 8, ko1 = ko0 + 32;
  const int vo0 = c * 2048 + q * 8,     vo1 = vo0 + 16 * 2048;
  const _Float16* bpb = BPre_b + (jbase + w * 4) * 32 + q * 8;

  // ---- prefetch tile-0 BPre ----
  half8_t pf0 = *reinterpret_cast<const half8_t*>(bpb);
  half8_t pf1 = *reinterpret_cast<const half8_t*>(bpb + 32);
  half8_t pf2 = *reinterpret_cast<const half8_t*>(bpb + 64);
  half8_t pf3 = *reinterpret_cast<const half8_t*>(bpb + 96);

  auto tile = [&](const int jt, _Float16* bH) {
    // ---- bias for this tile (bpf prefetched last iteration) ----
    _Float16* bW = bH + bwoff;
#pragma unroll
    for (int mt = 0; mt < 4; ++mt) {
      half8_t bpf = (mt == 0) ? pf0 : (mt == 1) ? pf1 : (mt == 2) ? pf2 : pf3;
      half8_t hvA = __builtin_elementwise_max(apfA - bpf, hzero8);
      f32x4 bcA = __builtin_amdgcn_mfma_f32_16x16x32_f16(hvA, w2f, z4, 0, 0, 0);
      half8_t hvB = __builtin_elementwise_max(apfB - bpf, hzero8);
      f32x4 bcB = __builtin_amdgcn_mfma_f32_16x16x32_f16(hvB, w2f, z4, 0, 0, 0);
      if (c < 8) {   // [h=c][j=w*4+mt][q*8: A4|B4], j-stride 36, h-stride 1160
        half4_t b4;
        b4[0] = (_Float16)bcA[0]; b4[1] = (_Float16)bcA[1];
        b4[2] = (_Float16)bcA[2]; b4[3] = (_Float16)bcA[3];
        *reinterpret_cast<half4_t*>(bW + mt * 36) = b4;
        half4_t b5;
        b5[0] = (_Float16)bcB[0]; b5[1] = (_Float16)bcB[1];
        b5[2] = (_Float16)bcB[2]; b5[3] = (_Float16)bcB[3];
        *reinterpret_cast<half4_t*>(bW + mt * 36 + 4) = b5;
      }
    }

    // ---- K/V fragments; scores ----
    const _Float16* kbase = kb0 + jt * 1024;
    const _Float16* vbase = vb0 + jt * 32;
    half8_t kf0 = *reinterpret_cast<const half8_t*>(kbase + ko0);
    half8_t kf1 = *reinterpret_cast<const half8_t*>(kbase + ko1);
    half8_t vf0 = *reinterpret_cast<const half8_t*>(vbase + vo0);
    half8_t vf1 = *reinterpret_cast<const half8_t*>(vbase + vo1);
    f32x4 sA0 = __builtin_amdgcn_mfma_f32_16x16x32_f16(qfA, kf0, z4, 0, 0, 0);
    f32x4 sA1 = __builtin_amdgcn_mfma_f32_16x16x32_f16(qfA, kf1, z4, 0, 0, 0);
    f32x4 sB0 = __builtin_amdgcn_mfma_f32_16x16x32_f16(qfB, kf0, z4, 0, 0, 0);
    f32x4 sB1 = __builtin_amdgcn_mfma_f32_16x16x32_f16(qfB, kf1, z4, 0, 0, 0);

    // ---- prefetch next tile's BPre (consumed next iteration) ----
    {
      const _Float16* bp = bpb + ((jt < 15) ? (jt + 1) : jt) * 1024;
      pf0 = *reinterpret_cast<const half8_t*>(bp);
      pf1 = *reinterpret_cast<const half8_t*>(bp + 32);
      pf2 = *reinterpret_cast<const half8_t*>(bp + 64);
      pf3 = *reinterpret_cast<const half8_t*>(bp + 96);
    }

    __syncthreads();   // bias[this tile] visible (sole barrier)

    const _Float16* bR = bH + broff;
    half8_t ab0  = *reinterpret_cast<const half8_t*>(bR);       // j=2c: A|B
    half4_t bbA1 = *reinterpret_cast<const half4_t*>(bR + 36);  // j=2c+1 A
    half4_t bbB1 = *reinterpret_cast<const half4_t*>(bR + 40);  // j=2c+1 B

    // ---- stream A: svm/exp -> EARLY pbuf store -> trigger (rare: redo) ----
    {
      float svm0[4], svm1[4], p0[4], p1[4];
#pragma unroll
      for (int r = 0; r < 4; ++r) {
        svm0[r] = fmaf(sA0[r], KSCALE, (float)ab0[r] - mA[r]);
        svm1[r] = fmaf(sA1[r], KSCALE, (float)bbA1[r] - mA[r]);
        p0[r] = EXP2F(svm0[r]);
        p1[r] = EXP2F(svm1[r]);
      }
#pragma unroll
      for (int r = 0; r < 4; ++r) {        // early store, no branch gate
        h2 pp; pp[0] = (_Float16)p0[r]; pp[1] = (_Float16)p1[r];
        *reinterpret_cast<h2*>(pbA + pwo + r * 32) = pp;
      }
      float need = fmaxf(fmaxf(fmaxf(svm0[0], svm1[0]), fmaxf(svm0[1], svm1[1])),
                         fmaxf(fmaxf(svm0[2], svm1[2]), fmaxf(svm0[3], svm1[3])));
      if (__any(need > 4.0f)) {   // rare: full row reduce + rescale + re-store
        float mr[4];
#pragma unroll
        for (int r = 0; r < 4; ++r) mr[r] = fmaxf(svm0[r], svm1[r]) + mA[r];
        h2 pk01, pk23;
        pk01[0] = (_Float16)mr[0]; pk01[1] = (_Float16)mr[1];
        pk23[0] = (_Float16)mr[2]; pk23[1] = (_Float16)mr[3];
        pk01 = rowmax16_h2(pk01);
        pk23 = rowmax16_h2(pk23);
        float mred[4] = {(float)pk01[0], (float)pk01[1],
                         (float)pk23[0], (float)pk23[1]};
#pragma unroll
        for (int r = 0; r < 4; ++r) {
          const float mnew = fmaxf(mA[r], mred[r]);
          const float alpha = EXP2F(mA[r] - mnew);
          p0[r] *= alpha; p1[r] *= alpha;
          lpA[r] *= alpha;
          O0A[r] *= alpha; O1A[r] *= alpha;
          mA[r] = mnew;
          h2 pp; pp[0] = (_Float16)p0[r]; pp[1] = (_Float16)p1[r];
          *reinterpret_cast<h2*>(pbA + pwo + r * 32) = pp;
        }
      }
    }
    // ---- stream B ----
    {
      float svm0[4], svm1[4], p0[4], p1[4];
#pragma unroll
      for (int r = 0; r < 4; ++r) {
        svm0[r] = fmaf(sB0[r], KSCALE, (float)ab0[4 + r] - mB[r]);
        svm1[r] = fmaf(sB1[r], KSCALE, (float)bbB1[r] - mB[r]);
        p0[r] = EXP2F(svm0[r]);
        p1[r] = EXP2F(svm1[r]);
      }
#pragma unroll
      for (int r = 0; r < 4; ++r) {
        h2 pp; pp[0] = (_Float16)p0[r]; pp[1] = (_Float16)p1[r];
        *reinterpret_cast<h2*>(pbB + pwo + r * 32) = pp;
      }
      float need = fmaxf(fmaxf(fmaxf(svm0[0], svm1[0]), fmaxf(svm0[1], svm1[1])),
                         fmaxf(fmaxf(svm0[2], svm1[2]), fmaxf(svm0[3], svm1[3])));
      if (__any(need > 4.0f)) {
        float mr[4];
#pragma unroll
        for (int r = 0; r < 4; ++r) mr[r] = fmaxf(svm0[r], svm1[r]) + mB[r];
        h2 pk01, pk23;
        pk01[0] = (_Float16)mr[0]; pk01[1] = (_Float16)mr[1];
        pk23[0] = (_Float16)mr[2]; pk23[1] = (_Float16)mr[3];
        pk01 = rowmax16_h2(pk01);
        pk23 = rowmax16_h2(pk23);
        float mred[4] = {(float)pk01[0], (float)pk01[1],
                         (float)pk23[0], (float)pk23[1]};
#pragma unroll
        for (int r = 0; r < 4; ++r) {
          const float mnew = fmaxf(mB[r], mred[r]);
          const float alpha = EXP2F(mB[r] - mnew);
          p0[r] *= alpha; p1[r] *= alpha;
          lpB[r] *= alpha;
          O0B[r] *= alpha; O1B[r] *= alpha;
          mB[r] = mnew;
          h2 pp; pp[0] = (_Float16)p0[r]; pp[1] = (_Float16)p1[r];
          *reinterpret_cast<h2*>(pbB + pwo + r * 32) = pp;
        }
      }
    }

    // wave-private pbuf: order writes before reads (LDS only — no vmcnt drain)
    asm volatile("s_waitcnt lgkmcnt(0)" ::: "memory");
    __builtin_amdgcn_sched_barrier(0);

    half8_t pfAx = *reinterpret_cast<const half8_t*>(pbA + pro);
    half8_t pfBx = *reinterpret_cast<const half8_t*>(pbB + pro);
    O0A = __builtin_amdgcn_mfma_f32_16x16x32_f16(pfAx, vf0, O0A, 0, 0, 0);
    O1A = __builtin_amdgcn_mfma_f32_16x16x32_f16(pfAx, vf1, O1A, 0, 0, 0);
    O0B = __builtin_amdgcn_mfma_f32_16x16x32_f16(pfBx, vf0, O0B, 0, 0, 0);
    O1B = __builtin_amdgcn_mfma_f32_16x16x32_f16(pfBx, vf1, O1B, 0, 0, 0);
    lpA = __builtin_amdgcn_mfma_f32_16x16x32_f16(pfAx, ones8, lpA, 0, 0, 0);
    lpB = __builtin_amdgcn_mfma_f32_16x16x32_f16(pfBx, ones8, lpB, 0, 0, 0);
  };

  // unroll-by-2: dbuf halves are compile-time per call site
  for (int pt = 0; pt < 8; ++pt) {
    tile(2 * pt,     biasH);
    tile(2 * pt + 1, biasH + 9280);
  }

  // ---- finalize: lp already full row sums (ones-MFMA); no lane reduce ----
#pragma unroll
  for (int r = 0; r < 4; ++r) {
    const float s = lpA[r];
    const float inv = 1.f / s;
    const int n = i0 + q * 4 + r;
    const long base = (long)(((chunk * 2 + b) * 8 + w) * 2048 + n);
    Opart[base * 32 + c]      = (_Float16)(O0A[r] * inv);
    Opart[base * 32 + 16 + c] = (_Float16)(O1A[r] * inv);
    if (c == 0) Mpart[base] = mA[r] + __log2f(s);
  }
#pragma unroll
  for (int r = 0; r < 4; ++r) {
    const float s = lpB[r];
    const float inv = 1.f / s;
    const int n = i0 + 16 + q * 4 + r;
    const long base = (long)(((chunk * 2 + b) * 8 + w) * 2048 + n);
    Opart[base * 32 + c]      = (_Float16)(O0B[r] * inv);
    Opart[base * 32 + 16 + c] = (_Float16)(O1B[r] * inv);
    if (c == 0) Mpart[base] = mB[r] + __log2f(s);
  }
}

// ---------------------------------------------------------------------------
// combine_proj: fused merge of 4 j-chunk partials -> LDS -> proj GEMM.
// ---------------------------------------------------------------------------
__global__ __launch_bounds__(256) void combine_proj(
    const _Float16* __restrict__ Opart, const float* __restrict__ Mpart,
    const _Float16* __restrict__ WoutT, const float* __restrict__ bout,
    float* __restrict__ out)
{
  __shared__ _Float16 aT[16][264];   // 16 rows x 256 cols, +8 pad
  const int i0 = blockIdx.x * 16;    // global row in [0,4096)
  const int b = i0 >> 11;
  const int n0 = i0 & 2047;
  const int tid = threadIdx.x;
  {
    const int row = tid >> 4, cg = tid & 15;   // col group: cols cg*16..+15
    const int n = n0 + row;
    const int h = cg >> 1;
    const int d0 = (cg & 1) * 16;
    float mv[4], M = -INFINITY;
#pragma unroll
    for (int ck = 0; ck < 4; ++ck) {
      mv[ck] = Mpart[((ck * 2 + b) * 8 + h) * 2048 + n];
      M = fmaxf(M, mv[ck]);
    }
    float num[16];
#pragma unroll
    for (int e = 0; e < 16; ++e) num[e] = 0.f;
    float den = 0.f;
#pragma unroll
    for (int ck = 0; ck < 4; ++ck) {
      const float wgt = EXP2F(mv[ck] - M);
      const _Float16* op = Opart +
          (long)(((ck * 2 + b) * 8 + h) * 2048 + n) * 32 + d0;
      half8_t o0v = *reinterpret_cast<const half8_t*>(op);
      half8_t o1v = *reinterpret_cast<const half8_t*>(op + 8);
#pragma unroll
      for (int e = 0; e < 8; ++e) {
        num[e]     += wgt * (float)o0v[e];
        num[8 + e] += wgt * (float)o1v[e];
      }
      den += wgt;
    }
    const float inv = 1.f / den;
    half8_t h0, h1;
#pragma unroll
    for (int e = 0; e < 8; ++e) {
      h0[e] = (_Float16)(num[e] * inv);
      h1[e] = (_Float16)(num[8 + e] * inv);
    }
    *reinterpret_cast<half8_t*>(&aT[row][cg * 16])     = h0;
    *reinterpret_cast<half8_t*>(&aT[row][cg * 16 + 8]) = h1;
  }
  __syncthreads();

  // ---- proj GEMM: wave does 16i x 64o (4 tiles), A from LDS ----
  const int o0 = (tid >> 6) * 64;
  const int lane = tid & 63, q = lane >> 4, c = lane & 15;
  f32x4 acc[4] = {{0,0,0,0},{0,0,0,0},{0,0,0,0},{0,0,0,0}};
  const _Float16* brow = WoutT + (o0 + c) * 256;
#pragma unroll
  for (int k0 = 0; k0 < 256; k0 += 32) {
    half8_t af = *reinterpret_cast<const half8_t*>(&aT[c][k0 + q * 8]);
#pragma unroll
    for (int t = 0; t < 4; ++t) {
      half8_t bf = *reinterpret_cast<const half8_t*>(brow + t * 16 * 256 + k0 + q * 8);
      acc[t] = __builtin_amdgcn_mfma_f32_16x16x32_f16(af, bf, acc[t], 0, 0, 0);
    }
  }
#pragma unroll
  for (int t = 0; t < 4; ++t) {
    const float bo = bout[o0 + t * 16 + c];
#pragma unroll
    for (int r = 0; r < 4; ++r)
      out[(i0 + q * 4 + r) * 256 + o0 + t * 16 + c] = acc[t][r] + bo;
  }
}

// ---------------------------------------------------------------------------
extern "C" void kernel_launch(void* const* d_in, const int* in_sizes, int n_in,
                              void* d_out, int out_size, void* d_ws, size_t ws_size,
                              hipStream_t stream)
{
  const float* x      = (const float*)d_in[0];
  const float* coords = (const float*)d_in[1];
  const float* Wqkv   = (const float*)d_in[2];
  const float* Wout   = (const float*)d_in[3];
  const float* bout   = (const float*)d_in[4];
  const float* pw1    = (const float*)d_in[5];
  const float* pb1    = (const float*)d_in[6];
  const float* pw2    = (const float*)d_in[7];
  const float* sw1    = (const float*)d_in[9];
  const float* sb1    = (const float*)d_in[10];
  const float* sw2    = (const float*)d_in[11];
  float* out = (float*)d_out;

  char* ws = (char*)d_ws;
  _Float16* Qh      = (_Float16*)(ws + 0);         // 2 MB
  _Float16* Kh      = (_Float16*)(ws + 2097152);   // 2 MB
  _Float16* Vt      = (_Float16*)(ws + 4194304);   // 2 MB
  _Float16* WqkvT   = (_Float16*)(ws + 8388608);   // 384 KB
  _Float16* WoutT   = (_Float16*)(ws + 8781824);   // 128 KB
  _Float16* APre    = (_Float16*)(ws + 8912896);   // 256 KB
  _Float16* BPre    = (_Float16*)(ws + 9175040);   // 256 KB
  _Float16* Opart   = (_Float16*)(ws + 9437184);   // 8 MB  [4][2][8][2048][32]
  float*    Mpart   = (float*)   (ws + 17825792);  // 512 KB [4][2][8][2048]

  prep_misc<<<80, 256, 0, stream>>>(Wqkv, Wout, coords, pw1, pb1, sw1, sb1,
                                    WqkvT, WoutT, APre, BPre);
  qkv_gemm<<<768, 256, 0, stream>>>(x, WqkvT, Qh, Kh, Vt);
  flash<<<512, 512, 0, stream>>>(Qh, Kh, Vt, APre, BPre, pw2, sw2, Opart, Mpart);
  combine_proj<<<256, 256, 0, stream>>>(Opart, Mpart, WoutT, bout, out);
}